// Round 6
// baseline (55.405 us; speedup 1.0000x reference)
//
#include <hip/hip_runtime.h>
#include <math.h>

#define BB 4
#define TT 2048
#define DM 768
#define HD 64
#define NROW (BB*TT)   // 8192
#define WFRAG_HALF ((size_t)24*12*512)   // 147456 elems per part (hi | lo)

typedef __attribute__((ext_vector_type(8))) short bf16x8;
typedef __attribute__((ext_vector_type(4))) float f32x4;

__device__ __forceinline__ unsigned short f2bf(float f) {
    unsigned int u = __float_as_uint(f);
    u += 0x7FFFu + ((u >> 16) & 1u);   // RNE
    return (unsigned short)(u >> 16);
}
__device__ __forceinline__ float bf2f(unsigned short h) {
    return __uint_as_float(((unsigned int)h) << 16);
}

// async 16B global->LDS: LDS dest is wave-uniform base + lane*16; global src per-lane
__device__ __forceinline__ void g2lds16(const unsigned short* g, unsigned short* l) {
    __builtin_amdgcn_global_load_lds(
        (const __attribute__((address_space(1))) unsigned int*)g,
        (__attribute__((address_space(3))) unsigned int*)l, 16, 0, 0);
}

// -------- W -> fragment-ordered bf16 hi/lo, layout [kc(24)][nt(12)][512] --------
__global__ __launch_bounds__(256) void wconv_kernel(
    const float* __restrict__ Wq, const float* __restrict__ Wk,
    const float* __restrict__ Wv, unsigned short* __restrict__ wfrag)
{
    __shared__ float ws[32][69];
    const int blk = blockIdx.x;          // 0..71 = m*24 + kc
    const int m = blk / 24, kc = blk % 24;
    const float* Wm = (m == 0) ? Wq : ((m == 1) ? Wk : Wv);
    const float sc = (m == 0) ? 0.125f : 1.0f;
    const int tid = threadIdx.x;
    {
        int r = tid >> 3, c0 = (tid & 7) * 8;
        *(float4*)&ws[r][c0]     = *(const float4*)(Wm + (size_t)(32*kc + r)*HD + c0);
        *(float4*)&ws[r][c0 + 4] = *(const float4*)(Wm + (size_t)(32*kc + r)*HD + c0 + 4);
    }
    __syncthreads();
    const int ntm = tid >> 6, lane = tid & 63;
    const int q15 = lane & 15, g = lane >> 4;
    const int col = 16*ntm + q15;
    bf16x8 hi, lo;
    #pragma unroll
    for (int j = 0; j < 8; ++j) {
        float w = ws[8*g + j][col] * sc;
        unsigned short h = f2bf(w);
        hi[j] = (short)h;
        lo[j] = (short)f2bf(w - bf2f(h));
    }
    size_t base = ((size_t)(kc*12 + m*4 + ntm))*512 + (size_t)lane*8;
    *(bf16x8*)(wfrag + base) = hi;
    *(bf16x8*)(wfrag + WFRAG_HALF + base) = lo;
}

// -------- QKV projection: x fully LDS-resident, W async-staged (dbuf) --------
// grid 256 x 512thr. Wave w: mt = w&1 (row half), nt = 3*(w>>1)+i, i=0..2.
__global__ __launch_bounds__(512) void proj_mfma_kernel(
    const float* __restrict__ x, const unsigned short* __restrict__ wfrag,
    const float* __restrict__ bq, const float* __restrict__ bk,
    const float* __restrict__ bv,
    unsigned short* __restrict__ qo, unsigned short* __restrict__ ko,
    unsigned short* __restrict__ vT)
{
    __shared__ unsigned short xsh[2][32][776];    // [hi/lo][row][k], +8 pad
    __shared__ unsigned short wsh[2][24*512];     // [buf][(part*12+nt)*512 + lane*8]
    const int tid  = threadIdx.x;
    const int wv   = tid >> 6;
    const int lane = tid & 63;
    const int q15  = lane & 15;
    const int g    = lane >> 4;
    const int row0 = blockIdx.x * 32;
    const int mt   = wv & 1;
    const int nt0  = 3 * (wv >> 1);
    const int xrow = 16*mt + q15;

    // ---- x init: 32 rows x 768 cols fp32 -> bf16 hi/lo LDS (once) ----
    {
        const int r  = tid >> 4;           // 0..31
        const int c4 = (tid & 15) * 4;     // float4 col base, stride 64
        const float* xp = x + (size_t)(row0 + r)*DM + c4;
        #pragma unroll
        for (int p = 0; p < 12; ++p) {
            float4 xv = *(const float4*)(xp + 64*p);
            float f[4] = {xv.x, xv.y, xv.z, xv.w};
            ushort4 hi, lo;
            unsigned short h;
            h = f2bf(f[0]); hi.x = h; lo.x = f2bf(f[0] - bf2f(h));
            h = f2bf(f[1]); hi.y = h; lo.y = f2bf(f[1] - bf2f(h));
            h = f2bf(f[2]); hi.z = h; lo.z = f2bf(f[2] - bf2f(h));
            h = f2bf(f[3]); hi.w = h; lo.w = f2bf(f[3] - bf2f(h));
            *(ushort4*)&xsh[0][r][c4 + 64*p] = hi;
            *(ushort4*)&xsh[1][r][c4 + 64*p] = lo;
        }
    }
    // ---- async-stage W chunk kcg=0 into wsh[0]: wave w stages j=3w..3w+2 ----
    #pragma unroll
    for (int jj = 0; jj < 3; ++jj) {
        int j = 3*wv + jj;                 // 0..23 (0-11 hi, 12-23 lo)
        const unsigned short* src = wfrag
            + (j < 12 ? (size_t)j*512 : WFRAG_HALF + (size_t)(j - 12)*512)
            + (size_t)lane*8;
        g2lds16(src, &wsh[0][j*512]);
    }
    __syncthreads();

    f32x4 acc[3];
    #pragma unroll
    for (int i = 0; i < 3; ++i) acc[i] = (f32x4){0.f, 0.f, 0.f, 0.f};

    for (int kcg = 0; kcg < 24; ++kcg) {
        const int buf = kcg & 1;
        if (kcg < 23) {
            const int kn = kcg + 1;
            #pragma unroll
            for (int jj = 0; jj < 3; ++jj) {
                int j = 3*wv + jj;
                const unsigned short* src = wfrag
                    + (j < 12 ? (size_t)(kn*12 + j)*512
                              : WFRAG_HALF + (size_t)(kn*12 + j - 12)*512)
                    + (size_t)lane*8;
                g2lds16(src, &wsh[buf^1][j*512]);
            }
        }
        // compute kcg from LDS
        bf16x8 xfh = *(const bf16x8*)&xsh[0][xrow][kcg*32 + 8*g];
        bf16x8 xfl = *(const bf16x8*)&xsh[1][xrow][kcg*32 + 8*g];
        #pragma unroll
        for (int i = 0; i < 3; ++i) {
            const int nt = nt0 + i;
            bf16x8 wh = *(const bf16x8*)&wsh[buf][nt*512 + lane*8];
            bf16x8 wl = *(const bf16x8*)&wsh[buf][(12 + nt)*512 + lane*8];
            acc[i] = __builtin_amdgcn_mfma_f32_16x16x32_bf16(xfh, wh, acc[i], 0, 0, 0);
            acc[i] = __builtin_amdgcn_mfma_f32_16x16x32_bf16(xfl, wh, acc[i], 0, 0, 0);
            acc[i] = __builtin_amdgcn_mfma_f32_16x16x32_bf16(xfh, wl, acc[i], 0, 0, 0);
        }
        __syncthreads();   // drains vmcnt (staged loads) + lgkm before buffer swap
    }

    // epilogue: C col = 16*ntm + q15, rows = row0 + 16*mt + 4g + r
    const int b  = row0 >> 11;
    const int t0 = row0 & 2047;
    #pragma unroll
    for (int i = 0; i < 3; ++i) {
        int nt = nt0 + i, m = nt >> 2, ntm = nt & 3;
        int col = 16*ntm + q15;
        float bb = (m == 0) ? 0.125f*bq[col] : ((m == 1) ? bk[col] : bv[col]);
        if (m == 2) {
            ushort4 pk;
            pk.x = f2bf(acc[i][0] + bb);
            pk.y = f2bf(acc[i][1] + bb);
            pk.z = f2bf(acc[i][2] + bb);
            pk.w = f2bf(acc[i][3] + bb);
            *(ushort4*)(vT + ((size_t)b*HD + col)*TT + t0 + 16*mt + 4*g) = pk;
        } else {
            unsigned short* op = (m == 0) ? qo : ko;
            #pragma unroll
            for (int r = 0; r < 4; ++r)
                op[(size_t)(row0 + 16*mt + 4*g + r)*HD + col] = f2bf(acc[i][r] + bb);
        }
    }
}

// -------- Flash attention: bf16 MFMA, in-block 4-way key split (unchanged) --------
__global__ __launch_bounds__(256) void attn_mfma_kernel(
    const unsigned short* __restrict__ qb_, const unsigned short* __restrict__ kb_,
    const unsigned short* __restrict__ vt_, float* __restrict__ out)
{
    __shared__ unsigned short plds[4][16][40];
    __shared__ float olds[4][16][66];
    __shared__ float mlds[4][16][2];

    const int tid  = threadIdx.x;
    const int wv   = tid >> 6;
    const int lane = tid & 63;
    const int q15  = lane & 15;
    const int g    = lane >> 4;

    const int bx = blockIdx.x;
    const int b  = bx & 3;
    const int qt = (TT/16 - 1) - (bx >> 2);
    const int qbase = qt * 16;
    const int nk = qbase + 16;

    const unsigned short* qp = qb_ + (size_t)b*TT*HD;
    const unsigned short* kp = kb_ + (size_t)b*TT*HD;
    const unsigned short* vp = vt_ + (size_t)b*HD*TT;

    bf16x8 qf[2];
    #pragma unroll
    for (int c = 0; c < 2; ++c)
        qf[c] = *(const bf16x8*)(qp + (size_t)(qbase + q15)*HD + 32*c + 8*g);

    f32x4 accv[4];
    #pragma unroll
    for (int h = 0; h < 4; ++h) accv[h] = (f32x4){0.f, 0.f, 0.f, 0.f};
    float m = -INFINITY, l = 0.f;

    const int ck = ((nk + 127) >> 7) << 5;
    const int kstart = wv * ck;
    const int kend = min(kstart + ck, nk);

    for (int k0 = kstart; k0 < kend; k0 += 32) {
        bf16x8 vf[4];
        #pragma unroll
        for (int h = 0; h < 4; ++h)
            vf[h] = *(const bf16x8*)(vp + (size_t)(16*h + q15)*TT + k0 + 8*g);
        bf16x8 kf[2][2];
        #pragma unroll
        for (int t = 0; t < 2; ++t)
            #pragma unroll
            for (int c = 0; c < 2; ++c)
                kf[t][c] = *(const bf16x8*)(kp + (size_t)(k0 + 16*t + q15)*HD + 32*c + 8*g);

        f32x4 st[2];
        #pragma unroll
        for (int t = 0; t < 2; ++t) {
            f32x4 z = {0.f, 0.f, 0.f, 0.f};
            st[t] = __builtin_amdgcn_mfma_f32_16x16x32_bf16(kf[t][0], qf[0], z, 0, 0, 0);
            st[t] = __builtin_amdgcn_mfma_f32_16x16x32_bf16(kf[t][1], qf[1], st[t], 0, 0, 0);
        }
        if (k0 + 31 > qbase) {
            int qabs = qbase + q15;
            #pragma unroll
            for (int t = 0; t < 2; ++t)
                #pragma unroll
                for (int r = 0; r < 4; ++r)
                    if (k0 + 16*t + 4*g + r > qabs) st[t][r] = -INFINITY;
        }
        float pmax = st[0][0];
        #pragma unroll
        for (int t = 0; t < 2; ++t)
            #pragma unroll
            for (int r = 0; r < 4; ++r) pmax = fmaxf(pmax, st[t][r]);
        pmax = fmaxf(pmax, __shfl_xor(pmax, 16));
        pmax = fmaxf(pmax, __shfl_xor(pmax, 32));
        float mnew = fmaxf(m, pmax);
        float mc = fmaxf(mnew, -1e30f);
        float alpha = __expf(m - mc);
        float p[2][4];
        float psum = 0.f;
        #pragma unroll
        for (int t = 0; t < 2; ++t)
            #pragma unroll
            for (int r = 0; r < 4; ++r) {
                p[t][r] = __expf(st[t][r] - mc);
                psum += p[t][r];
            }
        psum += __shfl_xor(psum, 16);
        psum += __shfl_xor(psum, 32);
        l = l * alpha + psum;
        m = mnew;
        float av[4];
        #pragma unroll
        for (int r = 0; r < 4; ++r) av[r] = __shfl(alpha, 4*g + r);
        #pragma unroll
        for (int h = 0; h < 4; ++h)
            #pragma unroll
            for (int r = 0; r < 4; ++r) accv[h][r] *= av[r];
        #pragma unroll
        for (int t = 0; t < 2; ++t) {
            ushort4 pk;
            pk.x = f2bf(p[t][0]); pk.y = f2bf(p[t][1]);
            pk.z = f2bf(p[t][2]); pk.w = f2bf(p[t][3]);
            *(ushort4*)&plds[wv][q15][16*t + 4*g] = pk;
        }
        bf16x8 pa = *(const bf16x8*)&plds[wv][q15][8*g];
        #pragma unroll
        for (int h = 0; h < 4; ++h)
            accv[h] = __builtin_amdgcn_mfma_f32_16x16x32_bf16(pa, vf[h], accv[h], 0, 0, 0);
    }

    #pragma unroll
    for (int h = 0; h < 4; ++h)
        #pragma unroll
        for (int r = 0; r < 4; ++r)
            olds[wv][4*g + r][16*h + q15] = accv[h][r];
    if (g == 0) { mlds[wv][q15][0] = m; mlds[wv][q15][1] = l; }
    __syncthreads();

    {
        int qq = tid >> 4;
        int c4 = (tid & 15) << 2;
        float mw[4], lw[4];
        #pragma unroll
        for (int w = 0; w < 4; ++w) { mw[w] = mlds[w][qq][0]; lw[w] = mlds[w][qq][1]; }
        float M = fmaxf(fmaxf(mw[0], mw[1]), fmaxf(mw[2], mw[3]));
        float Mc = fmaxf(M, -1e30f);
        float ww[4], ltot = 0.f;
        #pragma unroll
        for (int w = 0; w < 4; ++w) { ww[w] = __expf(mw[w] - Mc); ltot += ww[w]*lw[w]; }
        float invl = 1.f / ltot;
        float4 o;
        #pragma unroll
        for (int e = 0; e < 4; ++e) {
            float s = 0.f;
            #pragma unroll
            for (int w = 0; w < 4; ++w) s += ww[w] * olds[w][qq][c4 + e];
            ((float*)&o)[e] = s * invl;
        }
        *(float4*)(out + ((size_t)b*TT + qbase + qq)*HD + c4) = o;
    }
}

extern "C" void kernel_launch(void* const* d_in, const int* in_sizes, int n_in,
                              void* d_out, int out_size, void* d_ws, size_t ws_size,
                              hipStream_t stream) {
    const float* x  = (const float*)d_in[0];
    const float* Wq = (const float*)d_in[1];
    const float* bq = (const float*)d_in[2];
    const float* Wk = (const float*)d_in[3];
    const float* bk = (const float*)d_in[4];
    const float* Wv = (const float*)d_in[5];
    const float* bv = (const float*)d_in[6];
    float* out = (float*)d_out;

    unsigned short* qbf   = (unsigned short*)d_ws;
    unsigned short* kbf   = qbf + (size_t)NROW*HD;
    unsigned short* vT    = kbf + (size_t)NROW*HD;
    unsigned short* wfrag = vT  + (size_t)NROW*HD;   // 2*147456 elems = 576KB

    wconv_kernel<<<72, 256, 0, stream>>>(Wq, Wk, Wv, wfrag);
    proj_mfma_kernel<<<NROW/32, 512, 0, stream>>>(x, wfrag, bq, bk, bv, qbf, kbf, vT);
    attn_mfma_kernel<<<dim3(TT/16 * BB), 256, 0, stream>>>(qbf, kbf, vT, out);
}